// Round 4
// baseline (335.412 us; speedup 1.0000x reference)
//
#include <hip/hip_runtime.h>
#include <hip/hip_bf16.h>
#include <cstddef>

#define B_SZ 2
#define SEQ  2048
#define DM   1024
#define NH   16
#define HD   64
#define LAT  256
#define MTOT (B_SZ*SEQ)   // 4096
#define NQKV 1536
#define QSCALE 0.18033688011112042f  // 0.125 * log2(e)

typedef short bf16x8 __attribute__((ext_vector_type(8)));
typedef float floatx4 __attribute__((ext_vector_type(4)));
typedef unsigned short u16;

#if __has_builtin(__builtin_amdgcn_exp2f)
#define EXP2(x) __builtin_amdgcn_exp2f(x)
#else
#define EXP2(x) exp2f(x)
#endif

__device__ __forceinline__ u16 f2bf(float f) {
  union { float f; unsigned u; } a; a.f = f;
  unsigned r = a.u + 0x7FFFu + ((a.u >> 16) & 1u);  // RNE
  return (u16)(r >> 16);
}

__device__ __forceinline__ floatx4 mfma16(bf16x8 a, bf16x8 b, floatx4 c) {
  return __builtin_amdgcn_mfma_f32_16x16x32_bf16(a, b, c, 0, 0, 0);
}

// async global->LDS, 16B per lane; lds dest = wave-uniform base + lane*16
__device__ __forceinline__ void load16(const u16* g, u16* l) {
  __builtin_amdgcn_global_load_lds((const __attribute__((address_space(1))) unsigned*)g,
                                   (__attribute__((address_space(3))) unsigned*)l, 16, 0, 0);
}

// ---------------- mega prep: cast x | 6 weight transposes | bias concat ----------------
// one launch, branch on blockIdx.x; 256 threads
__device__ void transpose_tile(const float* __restrict__ W, u16* __restrict__ WT,
                               int K, int N, int k0, int n0, u16 (*t)[65]) {
  const int r = threadIdx.x >> 4;          // 0..15
  const int c4 = (threadIdx.x & 15) * 4;   // 0..60
#pragma unroll
  for (int s = 0; s < 4; s++) {
    int row = s * 16 + r;
    float4 v = *(const float4*)&W[(size_t)(k0 + row) * N + n0 + c4];
    t[row][c4 + 0] = f2bf(v.x); t[row][c4 + 1] = f2bf(v.y);
    t[row][c4 + 2] = f2bf(v.z); t[row][c4 + 3] = f2bf(v.w);
  }
  __syncthreads();
  const int r2 = threadIdx.x >> 2;          // 0..63 (out row = n)
  const int c8 = (threadIdx.x & 3) * 16;    // 0,16,32,48 (out col = k)
  __align__(16) u16 tmp[16];
#pragma unroll
  for (int i = 0; i < 16; i++) tmp[i] = t[c8 + i][r2];
  u16* dst = WT + (size_t)(n0 + r2) * K + k0 + c8;
  *(bf16x8*)dst       = *(const bf16x8*)&tmp[0];
  *(bf16x8*)(dst + 8) = *(const bf16x8*)&tmp[8];
}

__global__ __launch_bounds__(256)
void prep_k(const float* __restrict__ x, u16* __restrict__ xb,
            const float* __restrict__ Wq, const float* __restrict__ Wkd,
            const float* __restrict__ Wvd, const float* __restrict__ Wku,
            const float* __restrict__ Wvu, const float* __restrict__ Wo,
            u16* __restrict__ WstkT, u16* __restrict__ WkuT,
            u16* __restrict__ WvuT, u16* __restrict__ WoT,
            const float* __restrict__ bq, const float* __restrict__ bkd,
            const float* __restrict__ bvd, float* __restrict__ bqkv) {
  __shared__ u16 t[64][65];
  const int blk = blockIdx.x;
  if (blk < 4096) {                 // cast x -> bf16, 1 float4/thread
    int i = blk * 256 + threadIdx.x;
    float4 v = ((const float4*)x)[i];
    ushort4 o; o.x = f2bf(v.x); o.y = f2bf(v.y); o.z = f2bf(v.z); o.w = f2bf(v.w);
    ((ushort4*)xb)[i] = o;
  } else if (blk < 4352) {          // Wq^T -> WstkT[0:1024]
    int tt = blk - 4096;
    transpose_tile(Wq, WstkT, DM, DM, (tt >> 4) * 64, (tt & 15) * 64, t);
  } else if (blk < 4416) {          // Wkd^T -> WstkT[1024:1280]
    int tt = blk - 4352;
    transpose_tile(Wkd, WstkT + (size_t)DM * DM, DM, LAT, (tt >> 2) * 64, (tt & 3) * 64, t);
  } else if (blk < 4480) {          // Wvd^T -> WstkT[1280:1536]
    int tt = blk - 4416;
    transpose_tile(Wvd, WstkT + (size_t)1280 * DM, DM, LAT, (tt >> 2) * 64, (tt & 3) * 64, t);
  } else if (blk < 4544) {          // Wku^T
    int tt = blk - 4480;
    transpose_tile(Wku, WkuT, LAT, DM, (tt >> 4) * 64, (tt & 15) * 64, t);
  } else if (blk < 4608) {          // Wvu^T
    int tt = blk - 4544;
    transpose_tile(Wvu, WvuT, LAT, DM, (tt >> 4) * 64, (tt & 15) * 64, t);
  } else if (blk < 4864) {          // Wo^T
    int tt = blk - 4608;
    transpose_tile(Wo, WoT, DM, DM, (tt >> 4) * 64, (tt & 15) * 64, t);
  } else {                          // bias concat (6 blocks)
    int i = (blk - 4864) * 256 + threadIdx.x;
    float v = (i < 1024) ? bq[i] : (i < 1280) ? bkd[i - 1024] : bvd[i - 1280];
    bqkv[i] = v;
  }
}

// ---------------- GEMM: C = A * BT^T + bias (global_load_lds staging) ----------------
// VT1: when blockIdx.z==1, write C in VT[bh][d][s] layout (fused V-transpose).
template<int OUT_BF16, int VT1>
__global__ __launch_bounds__(256)
void gemm_bt(const u16* __restrict__ A0, const u16* __restrict__ A1,
             const u16* __restrict__ BT0, const u16* __restrict__ BT1,
             const float* __restrict__ bias0, const float* __restrict__ bias1,
             void* __restrict__ C0, void* __restrict__ C1,
             int M, int N, int Kd, int lda, float qscale, int qcols) {
  __shared__ u16 As[128 * 64];
  __shared__ u16 Bs[128 * 64];
  const u16* A  = blockIdx.z ? A1 : A0;
  const u16* BT = blockIdx.z ? BT1 : BT0;
  const float* bias = blockIdx.z ? bias1 : bias0;
  void* C = blockIdx.z ? C1 : C0;

  const int tid = threadIdx.x;
  const int m0 = blockIdx.y * 128, n0 = blockIdx.x * 128;
  const int wave = tid >> 6, lane = tid & 63;
  const int l15 = lane & 15, quad = lane >> 4;
  const int wm = (wave >> 1) * 64, wn = (wave & 1) * 64;

  floatx4 acc[4][4];
#pragma unroll
  for (int i = 0; i < 4; i++)
#pragma unroll
    for (int j = 0; j < 4; j++) acc[i][j] = (floatx4){0.f, 0.f, 0.f, 0.f};

  const int tr = tid >> 3;          // 0..31
  const int tc8 = (tid & 7) * 8;
  const u16* Ag = A  + (size_t)(m0 + tr) * lda + tc8;
  const u16* Bg = BT + (size_t)(n0 + tr) * Kd + tc8;
  u16* AsW = &As[(size_t)tid * 8];
  u16* BsW = &Bs[(size_t)tid * 8];

  for (int k0 = 0; k0 < Kd; k0 += 64) {
    __syncthreads();
#pragma unroll
    for (int s = 0; s < 4; s++) {
      load16(Ag + (size_t)(s * 32) * lda + k0, AsW + s * 2048);
      load16(Bg + (size_t)(s * 32) * Kd  + k0, BsW + s * 2048);
    }
    __syncthreads();
#pragma unroll
    for (int kk = 0; kk < 2; kk++) {
      bf16x8 af[4], bfr[4];
#pragma unroll
      for (int i = 0; i < 4; i++) {
        af[i]  = *(const bf16x8*)&As[(wm + i * 16 + l15) * 64 + kk * 32 + quad * 8];
        bfr[i] = *(const bf16x8*)&Bs[(wn + i * 16 + l15) * 64 + kk * 32 + quad * 8];
      }
#pragma unroll
      for (int i = 0; i < 4; i++)
#pragma unroll
        for (int j = 0; j < 4; j++)
          acc[i][j] = mfma16(af[i], bfr[j], acc[i][j]);
    }
  }

  if (VT1 && blockIdx.z == 1) {
    // write V in transposed per-head layout: VT[(b*16+h)*64+d][s]
#pragma unroll
    for (int i = 0; i < 4; i++) {
      int row = m0 + wm + i * 16 + quad * 4;    // b*2048 + s (s ≡ 0 mod 4)
      int bb = row >> 11, sb = row & 2047;
#pragma unroll
      for (int j = 0; j < 4; j++) {
        int col = n0 + wn + j * 16 + l15;       // h*64 + d
        float bv = bias[col];
        union { u16 u[4]; uint2 w2; } tv;
#pragma unroll
        for (int r = 0; r < 4; r++) tv.u[r] = f2bf(acc[i][j][r] + bv);
        *(uint2*)((u16*)C + ((size_t)(bb * 16 + (col >> 6)) * 64 + (col & 63)) * SEQ + sb) = tv.w2;
      }
    }
  } else {
#pragma unroll
    for (int i = 0; i < 4; i++) {
      int row = m0 + wm + i * 16 + quad * 4;
#pragma unroll
      for (int j = 0; j < 4; j++) {
        int col = n0 + wn + j * 16 + l15;
        float bv = bias[col];
        float sc = (col < qcols) ? qscale : 1.f;
#pragma unroll
        for (int r = 0; r < 4; r++) {
          float v = (acc[i][j][r] + bv) * sc;
          if (OUT_BF16) ((u16*)C)[(size_t)(row + r) * N + col] = f2bf(v);
          else          ((float*)C)[(size_t)(row + r) * N + col] = v;
        }
      }
    }
  }
}

// ---------------- fused attention ----------------
// grid (SEQ/64, B*NH), 4 waves share a 64-row q-tile; wave w handles keys [w*512,(w+1)*512).
// Fixed-shift softmax. Sᵀ=K·Qᵀ; P C-layout -> B-operand via wave-private LDS roundtrip.
// Combine via single 17KB LDS buffer, serial wave accumulate (LDS 23.5KB -> ~5 blocks/CU).
__global__ __launch_bounds__(256, 4)
void attn_fused(const u16* __restrict__ Q, const u16* __restrict__ K,
                const u16* __restrict__ VT, u16* __restrict__ CTX) {
  __shared__ float Ocmb[64][68];
  __shared__ float Lw[4][64];
  __shared__ u16 Plds[4][16][40];   // [wave][q][key(32), stride 40]
  const int bh = blockIdx.y, b = bh >> 4, h = bh & 15;
  const int wave = threadIdx.x >> 6, lane = threadIdx.x & 63;
  const int l15 = lane & 15, quad = lane >> 4;
  const int q0 = blockIdx.x * 64;

  // Q as B-operand: qf[qi][h2] elem j = Q[q0+qi*16+l15][h*64 + h2*32 + quad*8 + j]
  bf16x8 qf[4][2];
  {
    const u16* Qp = Q + (size_t)(b * SEQ + q0 + l15) * NQKV + h * HD + quad * 8;
#pragma unroll
    for (int qi = 0; qi < 4; qi++)
#pragma unroll
      for (int h2 = 0; h2 < 2; h2++)
        qf[qi][h2] = *(const bf16x8*)(Qp + (size_t)qi * 16 * NQKV + h2 * 32);
  }
  const u16* Kp = K + (size_t)(b * SEQ) * DM + h * HD + quad * 8;
  const u16* Vp = VT + ((size_t)bh * HD + l15) * SEQ + quad * 8;

  floatx4 o[4][4];   // o[dt][qi]: ctxᵀ (rows = dim, cols = q)
#pragma unroll
  for (int dt = 0; dt < 4; dt++)
#pragma unroll
    for (int qi = 0; qi < 4; qi++) o[dt][qi] = (floatx4){0.f, 0.f, 0.f, 0.f};
  float ls[4] = {0.f, 0.f, 0.f, 0.f};

  const int kb0 = wave * 512;

  for (int it = 0; it < 16; ++it) {
    const int kb = kb0 + it * 32;
    bf16x8 kf[2][2];
#pragma unroll
    for (int ki = 0; ki < 2; ki++)
#pragma unroll
      for (int h2 = 0; h2 < 2; h2++)
        kf[ki][h2] = *(const bf16x8*)(Kp + (size_t)(kb + ki * 16 + l15) * DM + h2 * 32);
    bf16x8 vf[4];
#pragma unroll
    for (int dt = 0; dt < 4; dt++)
      vf[dt] = *(const bf16x8*)(Vp + (size_t)(dt * 16) * SEQ + kb);

#pragma unroll
    for (int qi = 0; qi < 4; qi++) {
      unsigned pk[2][2];
#pragma unroll
      for (int ki = 0; ki < 2; ki++) {
        floatx4 z = (floatx4){0.f, 0.f, 0.f, 0.f};
        z = mfma16(kf[ki][0], qf[qi][0], z);
        z = mfma16(kf[ki][1], qf[qi][1], z);
        float p0 = EXP2(z[0]), p1 = EXP2(z[1]), p2 = EXP2(z[2]), p3 = EXP2(z[3]);
        ls[qi] += (p0 + p1) + (p2 + p3);
        unsigned u0 = __float_as_uint(p0) + 0x8000u;
        unsigned u1 = __float_as_uint(p1) + 0x8000u;
        unsigned u2 = __float_as_uint(p2) + 0x8000u;
        unsigned u3 = __float_as_uint(p3) + 0x8000u;
        pk[ki][0] = __builtin_amdgcn_perm(u1, u0, 0x07060302u);
        pk[ki][1] = __builtin_amdgcn_perm(u3, u2, 0x07060302u);
      }
      {
        uint2 w0; w0.x = pk[0][0]; w0.y = pk[0][1];
        *(uint2*)&Plds[wave][l15][quad * 4] = w0;
        uint2 w1; w1.x = pk[1][0]; w1.y = pk[1][1];
        *(uint2*)&Plds[wave][l15][16 + quad * 4] = w1;
      }
      bf16x8 pf = *(const bf16x8*)&Plds[wave][l15][quad * 8];
#pragma unroll
      for (int dt = 0; dt < 4; dt++)
        o[dt][qi] = mfma16(vf[dt], pf, o[dt][qi]);
    }
  }

  // ---- per-wave l reduction ----
#pragma unroll
  for (int qi = 0; qi < 4; qi++) {
    float v = ls[qi];
    v += __shfl_xor(v, 16);
    v += __shfl_xor(v, 32);
    if (quad == 0) Lw[wave][qi * 16 + l15] = v;
  }
  // ---- serial combine through one buffer ----
  if (wave == 0) {
#pragma unroll
    for (int dt = 0; dt < 4; dt++)
#pragma unroll
      for (int qi = 0; qi < 4; qi++)
        *(floatx4*)&Ocmb[qi * 16 + l15][dt * 16 + quad * 4] = o[dt][qi];
  }
  __syncthreads();
  if (wave == 1) {
#pragma unroll
    for (int dt = 0; dt < 4; dt++)
#pragma unroll
      for (int qi = 0; qi < 4; qi++) {
        floatx4* pp = (floatx4*)&Ocmb[qi * 16 + l15][dt * 16 + quad * 4];
        *pp = *pp + o[dt][qi];
      }
  }
  __syncthreads();
  if (wave == 2) {
#pragma unroll
    for (int dt = 0; dt < 4; dt++)
#pragma unroll
      for (int qi = 0; qi < 4; qi++) {
        floatx4* pp = (floatx4*)&Ocmb[qi * 16 + l15][dt * 16 + quad * 4];
        *pp = *pp + o[dt][qi];
      }
  }
  __syncthreads();
  if (wave == 3) {
#pragma unroll
    for (int qi = 0; qi < 4; qi++) {
      int qq = qi * 16 + l15;
      float lt = Lw[0][qq] + Lw[1][qq] + Lw[2][qq] + Lw[3][qq];
      float inv = 1.f / lt;
      u16* Crow = CTX + (size_t)(b * SEQ + q0 + qq) * DM + h * HD + quad * 4;
#pragma unroll
      for (int dt = 0; dt < 4; dt++) {
        floatx4 ov = o[dt][qi] + *(const floatx4*)&Ocmb[qq][dt * 16 + quad * 4];
        union { u16 u[4]; uint2 w2; } tv;
#pragma unroll
        for (int r = 0; r < 4; r++) tv.u[r] = f2bf(ov[r] * inv);
        *(uint2*)(Crow + dt * 16) = tv.w2;
      }
    }
  }
}

// ---------------- launch ----------------
extern "C" void kernel_launch(void* const* d_in, const int* in_sizes, int n_in,
                              void* d_out, int out_size, void* d_ws, size_t ws_size,
                              hipStream_t stream) {
  const float* x   = (const float*)d_in[0];
  const float* Wq  = (const float*)d_in[1];
  const float* bq  = (const float*)d_in[2];
  const float* Wkd = (const float*)d_in[3];
  const float* bkd = (const float*)d_in[4];
  const float* Wvd = (const float*)d_in[5];
  const float* bvd = (const float*)d_in[6];
  const float* Wku = (const float*)d_in[7];
  const float* bku = (const float*)d_in[8];
  const float* Wvu = (const float*)d_in[9];
  const float* bvu = (const float*)d_in[10];
  const float* Wo  = (const float*)d_in[11];
  const float* bo  = (const float*)d_in[12];
  float* out = (float*)d_out;

  float* bqkv = (float*)d_ws;
  u16* p = (u16*)((char*)d_ws + 1536 * sizeof(float));
  u16* xb    = p; p += (size_t)MTOT * DM;
  u16* WstkT = p; p += (size_t)NQKV * DM;           // WqT | WkdT | WvdT
  u16* WkuT  = p; p += (size_t)DM * LAT;
  u16* WvuT  = p; p += (size_t)DM * LAT;
  u16* WoT   = p; p += (size_t)DM * DM;
  u16* QKVb  = p; p += (size_t)MTOT * NQKV;         // Q(pre-scaled) | KL | VL
  u16* Kb    = p; p += (size_t)MTOT * DM;
  u16* VTb   = p; p += (size_t)MTOT * DM;
  u16* CXb   = p; p += (size_t)MTOT * DM;

  prep_k<<<4870, 256, 0, stream>>>(x, xb, Wq, Wkd, Wvd, Wku, Wvu, Wo,
                                   WstkT, WkuT, WvuT, WoT, bq, bkd, bvd, bqkv);

  gemm_bt<1, 0><<<dim3(NQKV / 128, MTOT / 128, 1), 256, 0, stream>>>(
      xb, xb, WstkT, WstkT, bqkv, bqkv, QKVb, QKVb, MTOT, NQKV, DM, DM, QSCALE, DM);
  // z=0: K-up -> Kb (row layout); z=1: V-up -> VTb (transposed per-head layout)
  gemm_bt<1, 1><<<dim3(DM / 128, MTOT / 128, 2), 256, 0, stream>>>(
      QKVb + 1024, QKVb + 1280, WkuT, WvuT, bku, bvu, Kb, VTb, MTOT, DM, LAT, NQKV, 1.f, 0);

  attn_fused<<<dim3(SEQ / 64, B_SZ * NH), 256, 0, stream>>>(QKVb, Kb, VTb, CXb);

  gemm_bt<0, 0><<<dim3(DM / 128, MTOT / 128, 1), 256, 0, stream>>>(
      CXb, CXb, WoT, WoT, bo, bo, out, out, MTOT, DM, DM, DM, 1.f, 0);
}

// Round 5
// 235.458 us; speedup vs baseline: 1.4245x; 1.4245x over previous
//
#include <hip/hip_runtime.h>
#include <hip/hip_bf16.h>
#include <cstddef>

#define B_SZ 2
#define SEQ  2048
#define DM   1024
#define NH   16
#define HD   64
#define LAT  256
#define MTOT (B_SZ*SEQ)   // 4096
#define NQKV 1536
#define QSCALE 0.18033688011112042f  // 0.125 * log2(e)

typedef short bf16x8 __attribute__((ext_vector_type(8)));
typedef float floatx4 __attribute__((ext_vector_type(4)));
typedef unsigned short u16;

#if __has_builtin(__builtin_amdgcn_exp2f)
#define EXP2(x) __builtin_amdgcn_exp2f(x)
#else
#define EXP2(x) exp2f(x)
#endif

__device__ __forceinline__ u16 f2bf(float f) {
  union { float f; unsigned u; } a; a.f = f;
  unsigned r = a.u + 0x7FFFu + ((a.u >> 16) & 1u);  // RNE
  return (u16)(r >> 16);
}

__device__ __forceinline__ floatx4 mfma16(bf16x8 a, bf16x8 b, floatx4 c) {
  return __builtin_amdgcn_mfma_f32_16x16x32_bf16(a, b, c, 0, 0, 0);
}

// async global->LDS, 16B per lane; lds dest = wave-uniform base + lane*16
__device__ __forceinline__ void load16(const u16* g, u16* l) {
  __builtin_amdgcn_global_load_lds((const __attribute__((address_space(1))) unsigned*)g,
                                   (__attribute__((address_space(3))) unsigned*)l, 16, 0, 0);
}

// ---------------- mega prep: cast x | 6 weight transposes | bias concat ----------------
__device__ void transpose_tile(const float* __restrict__ W, u16* __restrict__ WT,
                               int K, int N, int k0, int n0, u16 (*t)[65]) {
  const int r = threadIdx.x >> 4;          // 0..15
  const int c4 = (threadIdx.x & 15) * 4;   // 0..60
#pragma unroll
  for (int s = 0; s < 4; s++) {
    int row = s * 16 + r;
    float4 v = *(const float4*)&W[(size_t)(k0 + row) * N + n0 + c4];
    t[row][c4 + 0] = f2bf(v.x); t[row][c4 + 1] = f2bf(v.y);
    t[row][c4 + 2] = f2bf(v.z); t[row][c4 + 3] = f2bf(v.w);
  }
  __syncthreads();
  const int r2 = threadIdx.x >> 2;          // 0..63 (out row = n)
  const int c8 = (threadIdx.x & 3) * 16;    // 0,16,32,48 (out col = k)
  __align__(16) u16 tmp[16];
#pragma unroll
  for (int i = 0; i < 16; i++) tmp[i] = t[c8 + i][r2];
  u16* dst = WT + (size_t)(n0 + r2) * K + k0 + c8;
  *(bf16x8*)dst       = *(const bf16x8*)&tmp[0];
  *(bf16x8*)(dst + 8) = *(const bf16x8*)&tmp[8];
}

__global__ __launch_bounds__(256)
void prep_k(const float* __restrict__ x, u16* __restrict__ xb,
            const float* __restrict__ Wq, const float* __restrict__ Wkd,
            const float* __restrict__ Wvd, const float* __restrict__ Wku,
            const float* __restrict__ Wvu, const float* __restrict__ Wo,
            u16* __restrict__ WstkT, u16* __restrict__ WkuT,
            u16* __restrict__ WvuT, u16* __restrict__ WoT,
            const float* __restrict__ bq, const float* __restrict__ bkd,
            const float* __restrict__ bvd, float* __restrict__ bqkv) {
  __shared__ u16 t[64][65];
  const int blk = blockIdx.x;
  if (blk < 4096) {                 // cast x -> bf16, 1 float4/thread
    int i = blk * 256 + threadIdx.x;
    float4 v = ((const float4*)x)[i];
    ushort4 o; o.x = f2bf(v.x); o.y = f2bf(v.y); o.z = f2bf(v.z); o.w = f2bf(v.w);
    ((ushort4*)xb)[i] = o;
  } else if (blk < 4352) {          // Wq^T -> WstkT[0:1024]
    int tt = blk - 4096;
    transpose_tile(Wq, WstkT, DM, DM, (tt >> 4) * 64, (tt & 15) * 64, t);
  } else if (blk < 4416) {          // Wkd^T -> WstkT[1024:1280]
    int tt = blk - 4352;
    transpose_tile(Wkd, WstkT + (size_t)DM * DM, DM, LAT, (tt >> 2) * 64, (tt & 3) * 64, t);
  } else if (blk < 4480) {          // Wvd^T -> WstkT[1280:1536]
    int tt = blk - 4416;
    transpose_tile(Wvd, WstkT + (size_t)1280 * DM, DM, LAT, (tt >> 2) * 64, (tt & 3) * 64, t);
  } else if (blk < 4544) {          // Wku^T
    int tt = blk - 4480;
    transpose_tile(Wku, WkuT, LAT, DM, (tt >> 4) * 64, (tt & 15) * 64, t);
  } else if (blk < 4608) {          // Wvu^T
    int tt = blk - 4544;
    transpose_tile(Wvu, WvuT, LAT, DM, (tt >> 4) * 64, (tt & 15) * 64, t);
  } else if (blk < 4864) {          // Wo^T
    int tt = blk - 4608;
    transpose_tile(Wo, WoT, DM, DM, (tt >> 4) * 64, (tt & 15) * 64, t);
  } else {                          // bias concat (6 blocks)
    int i = (blk - 4864) * 256 + threadIdx.x;
    float v = (i < 1024) ? bq[i] : (i < 1280) ? bkd[i - 1024] : bvd[i - 1280];
    bqkv[i] = v;
  }
}

// ---------------- GEMM: C = A * BT^T + bias (global_load_lds staging) ----------------
// VT1: when blockIdx.z==1, write C in VT[bh][d][s] layout (fused V-transpose).
template<int OUT_BF16, int VT1>
__global__ __launch_bounds__(256)
void gemm_bt(const u16* __restrict__ A0, const u16* __restrict__ A1,
             const u16* __restrict__ BT0, const u16* __restrict__ BT1,
             const float* __restrict__ bias0, const float* __restrict__ bias1,
             void* __restrict__ C0, void* __restrict__ C1,
             int M, int N, int Kd, int lda, float qscale, int qcols) {
  __shared__ u16 As[128 * 64];
  __shared__ u16 Bs[128 * 64];
  const u16* A  = blockIdx.z ? A1 : A0;
  const u16* BT = blockIdx.z ? BT1 : BT0;
  const float* bias = blockIdx.z ? bias1 : bias0;
  void* C = blockIdx.z ? C1 : C0;

  const int tid = threadIdx.x;
  const int m0 = blockIdx.y * 128, n0 = blockIdx.x * 128;
  const int wave = tid >> 6, lane = tid & 63;
  const int l15 = lane & 15, quad = lane >> 4;
  const int wm = (wave >> 1) * 64, wn = (wave & 1) * 64;

  floatx4 acc[4][4];
#pragma unroll
  for (int i = 0; i < 4; i++)
#pragma unroll
    for (int j = 0; j < 4; j++) acc[i][j] = (floatx4){0.f, 0.f, 0.f, 0.f};

  const int tr = tid >> 3;          // 0..31
  const int tc8 = (tid & 7) * 8;
  const u16* Ag = A  + (size_t)(m0 + tr) * lda + tc8;
  const u16* Bg = BT + (size_t)(n0 + tr) * Kd + tc8;
  u16* AsW = &As[(size_t)tid * 8];
  u16* BsW = &Bs[(size_t)tid * 8];

  for (int k0 = 0; k0 < Kd; k0 += 64) {
    __syncthreads();
#pragma unroll
    for (int s = 0; s < 4; s++) {
      load16(Ag + (size_t)(s * 32) * lda + k0, AsW + s * 2048);
      load16(Bg + (size_t)(s * 32) * Kd  + k0, BsW + s * 2048);
    }
    __syncthreads();
#pragma unroll
    for (int kk = 0; kk < 2; kk++) {
      bf16x8 af[4], bfr[4];
#pragma unroll
      for (int i = 0; i < 4; i++) {
        af[i]  = *(const bf16x8*)&As[(wm + i * 16 + l15) * 64 + kk * 32 + quad * 8];
        bfr[i] = *(const bf16x8*)&Bs[(wn + i * 16 + l15) * 64 + kk * 32 + quad * 8];
      }
#pragma unroll
      for (int i = 0; i < 4; i++)
#pragma unroll
        for (int j = 0; j < 4; j++)
          acc[i][j] = mfma16(af[i], bfr[j], acc[i][j]);
    }
  }

  if (VT1 && blockIdx.z == 1) {
    // write V in transposed per-head layout: VT[(b*16+h)*64+d][s]
#pragma unroll
    for (int i = 0; i < 4; i++) {
      int row = m0 + wm + i * 16 + quad * 4;    // b*2048 + s (s ≡ 0 mod 4)
      int bb = row >> 11, sb = row & 2047;
#pragma unroll
      for (int j = 0; j < 4; j++) {
        int col = n0 + wn + j * 16 + l15;       // h*64 + d
        float bv = bias[col];
        union { u16 u[4]; uint2 w2; } tv;
#pragma unroll
        for (int r = 0; r < 4; r++) tv.u[r] = f2bf(acc[i][j][r] + bv);
        *(uint2*)((u16*)C + ((size_t)(bb * 16 + (col >> 6)) * 64 + (col & 63)) * SEQ + sb) = tv.w2;
      }
    }
  } else {
#pragma unroll
    for (int i = 0; i < 4; i++) {
      int row = m0 + wm + i * 16 + quad * 4;
#pragma unroll
      for (int j = 0; j < 4; j++) {
        int col = n0 + wn + j * 16 + l15;
        float bv = bias[col];
        float sc = (col < qcols) ? qscale : 1.f;
#pragma unroll
        for (int r = 0; r < 4; r++) {
          float v = (acc[i][j][r] + bv) * sc;
          if (OUT_BF16) ((u16*)C)[(size_t)(row + r) * N + col] = f2bf(v);
          else          ((float*)C)[(size_t)(row + r) * N + col] = v;
        }
      }
    }
  }
}

// ---------------- fused attention ----------------
// grid (SEQ/64, B*NH), 4 waves share a 64-row q-tile; wave w handles keys [w*512,(w+1)*512).
// Fixed-shift softmax. Sᵀ=K·Qᵀ; P C-layout -> B-operand via wave-private LDS roundtrip.
// LDS 23.5KB; launch_bounds(256,2): VGPR cap 256 (kernel needs ~92; DO NOT cap tighter —
// (256,4) forced 64 VGPRs -> 580MB scratch spill traffic, 2.3x slower [R4 post-mortem]).
__global__ __launch_bounds__(256, 2)
void attn_fused(const u16* __restrict__ Q, const u16* __restrict__ K,
                const u16* __restrict__ VT, u16* __restrict__ CTX) {
  __shared__ float Ocmb[64][68];
  __shared__ float Lw[4][64];
  __shared__ u16 Plds[4][16][40];   // [wave][q][key(32), stride 40]
  const int bh = blockIdx.y, b = bh >> 4, h = bh & 15;
  const int wave = threadIdx.x >> 6, lane = threadIdx.x & 63;
  const int l15 = lane & 15, quad = lane >> 4;
  const int q0 = blockIdx.x * 64;

  // Q as B-operand: qf[qi][h2] elem j = Q[q0+qi*16+l15][h*64 + h2*32 + quad*8 + j]
  bf16x8 qf[4][2];
  {
    const u16* Qp = Q + (size_t)(b * SEQ + q0 + l15) * NQKV + h * HD + quad * 8;
#pragma unroll
    for (int qi = 0; qi < 4; qi++)
#pragma unroll
      for (int h2 = 0; h2 < 2; h2++)
        qf[qi][h2] = *(const bf16x8*)(Qp + (size_t)qi * 16 * NQKV + h2 * 32);
  }
  const u16* Kp = K + (size_t)(b * SEQ) * DM + h * HD + quad * 8;
  const u16* Vp = VT + ((size_t)bh * HD + l15) * SEQ + quad * 8;

  floatx4 o[4][4];   // o[dt][qi]: ctxᵀ (rows = dim, cols = q)
#pragma unroll
  for (int dt = 0; dt < 4; dt++)
#pragma unroll
    for (int qi = 0; qi < 4; qi++) o[dt][qi] = (floatx4){0.f, 0.f, 0.f, 0.f};
  float ls[4] = {0.f, 0.f, 0.f, 0.f};

  const int kb0 = wave * 512;

  for (int it = 0; it < 16; ++it) {
    const int kb = kb0 + it * 32;
    bf16x8 kf[2][2];
#pragma unroll
    for (int ki = 0; ki < 2; ki++)
#pragma unroll
      for (int h2 = 0; h2 < 2; h2++)
        kf[ki][h2] = *(const bf16x8*)(Kp + (size_t)(kb + ki * 16 + l15) * DM + h2 * 32);
    bf16x8 vf[4];
#pragma unroll
    for (int dt = 0; dt < 4; dt++)
      vf[dt] = *(const bf16x8*)(Vp + (size_t)(dt * 16) * SEQ + kb);

#pragma unroll
    for (int qi = 0; qi < 4; qi++) {
      unsigned pk[2][2];
#pragma unroll
      for (int ki = 0; ki < 2; ki++) {
        floatx4 z = (floatx4){0.f, 0.f, 0.f, 0.f};
        z = mfma16(kf[ki][0], qf[qi][0], z);
        z = mfma16(kf[ki][1], qf[qi][1], z);
        float p0 = EXP2(z[0]), p1 = EXP2(z[1]), p2 = EXP2(z[2]), p3 = EXP2(z[3]);
        ls[qi] += (p0 + p1) + (p2 + p3);
        unsigned u0 = __float_as_uint(p0) + 0x8000u;
        unsigned u1 = __float_as_uint(p1) + 0x8000u;
        unsigned u2 = __float_as_uint(p2) + 0x8000u;
        unsigned u3 = __float_as_uint(p3) + 0x8000u;
        pk[ki][0] = __builtin_amdgcn_perm(u1, u0, 0x07060302u);
        pk[ki][1] = __builtin_amdgcn_perm(u3, u2, 0x07060302u);
      }
      {
        uint2 w0; w0.x = pk[0][0]; w0.y = pk[0][1];
        *(uint2*)&Plds[wave][l15][quad * 4] = w0;
        uint2 w1; w1.x = pk[1][0]; w1.y = pk[1][1];
        *(uint2*)&Plds[wave][l15][16 + quad * 4] = w1;
      }
      bf16x8 pf = *(const bf16x8*)&Plds[wave][l15][quad * 8];
#pragma unroll
      for (int dt = 0; dt < 4; dt++)
        o[dt][qi] = mfma16(vf[dt], pf, o[dt][qi]);
    }
  }

  // ---- per-wave l reduction ----
#pragma unroll
  for (int qi = 0; qi < 4; qi++) {
    float v = ls[qi];
    v += __shfl_xor(v, 16);
    v += __shfl_xor(v, 32);
    if (quad == 0) Lw[wave][qi * 16 + l15] = v;
  }
  // ---- serial combine through one buffer ----
  if (wave == 0) {
#pragma unroll
    for (int dt = 0; dt < 4; dt++)
#pragma unroll
      for (int qi = 0; qi < 4; qi++)
        *(floatx4*)&Ocmb[qi * 16 + l15][dt * 16 + quad * 4] = o[dt][qi];
  }
  __syncthreads();
  if (wave == 1) {
#pragma unroll
    for (int dt = 0; dt < 4; dt++)
#pragma unroll
      for (int qi = 0; qi < 4; qi++) {
        floatx4* pp = (floatx4*)&Ocmb[qi * 16 + l15][dt * 16 + quad * 4];
        *pp = *pp + o[dt][qi];
      }
  }
  __syncthreads();
  if (wave == 2) {
#pragma unroll
    for (int dt = 0; dt < 4; dt++)
#pragma unroll
      for (int qi = 0; qi < 4; qi++) {
        floatx4* pp = (floatx4*)&Ocmb[qi * 16 + l15][dt * 16 + quad * 4];
        *pp = *pp + o[dt][qi];
      }
  }
  __syncthreads();
  if (wave == 3) {
#pragma unroll
    for (int qi = 0; qi < 4; qi++) {
      int qq = qi * 16 + l15;
      float lt = Lw[0][qq] + Lw[1][qq] + Lw[2][qq] + Lw[3][qq];
      float inv = 1.f / lt;
      u16* Crow = CTX + (size_t)(b * SEQ + q0 + qq) * DM + h * HD + quad * 4;
#pragma unroll
      for (int dt = 0; dt < 4; dt++) {
        floatx4 ov = o[dt][qi] + *(const floatx4*)&Ocmb[qq][dt * 16 + quad * 4];
        union { u16 u[4]; uint2 w2; } tv;
#pragma unroll
        for (int r = 0; r < 4; r++) tv.u[r] = f2bf(ov[r] * inv);
        *(uint2*)(Crow + dt * 16) = tv.w2;
      }
    }
  }
}

// ---------------- launch ----------------
extern "C" void kernel_launch(void* const* d_in, const int* in_sizes, int n_in,
                              void* d_out, int out_size, void* d_ws, size_t ws_size,
                              hipStream_t stream) {
  const float* x   = (const float*)d_in[0];
  const float* Wq  = (const float*)d_in[1];
  const float* bq  = (const float*)d_in[2];
  const float* Wkd = (const float*)d_in[3];
  const float* bkd = (const float*)d_in[4];
  const float* Wvd = (const float*)d_in[5];
  const float* bvd = (const float*)d_in[6];
  const float* Wku = (const float*)d_in[7];
  const float* bku = (const float*)d_in[8];
  const float* Wvu = (const float*)d_in[9];
  const float* bvu = (const float*)d_in[10];
  const float* Wo  = (const float*)d_in[11];
  const float* bo  = (const float*)d_in[12];
  float* out = (float*)d_out;

  float* bqkv = (float*)d_ws;
  u16* p = (u16*)((char*)d_ws + 1536 * sizeof(float));
  u16* xb    = p; p += (size_t)MTOT * DM;
  u16* WstkT = p; p += (size_t)NQKV * DM;           // WqT | WkdT | WvdT
  u16* WkuT  = p; p += (size_t)DM * LAT;
  u16* WvuT  = p; p += (size_t)DM * LAT;
  u16* WoT   = p; p += (size_t)DM * DM;
  u16* QKVb  = p; p += (size_t)MTOT * NQKV;         // Q(pre-scaled) | KL | VL
  u16* Kb    = p; p += (size_t)MTOT * DM;
  u16* VTb   = p; p += (size_t)MTOT * DM;
  u16* CXb   = p; p += (size_t)MTOT * DM;

  prep_k<<<4870, 256, 0, stream>>>(x, xb, Wq, Wkd, Wvd, Wku, Wvu, Wo,
                                   WstkT, WkuT, WvuT, WoT, bq, bkd, bvd, bqkv);

  gemm_bt<1, 0><<<dim3(NQKV / 128, MTOT / 128, 1), 256, 0, stream>>>(
      xb, xb, WstkT, WstkT, bqkv, bqkv, QKVb, QKVb, MTOT, NQKV, DM, DM, QSCALE, DM);
  // z=0: K-up -> Kb (row layout); z=1: V-up -> VTb (transposed per-head layout)
  gemm_bt<1, 1><<<dim3(DM / 128, MTOT / 128, 2), 256, 0, stream>>>(
      QKVb + 1024, QKVb + 1280, WkuT, WvuT, bku, bvu, Kb, VTb, MTOT, DM, LAT, NQKV, 1.f, 0);

  attn_fused<<<dim3(SEQ / 64, B_SZ * NH), 256, 0, stream>>>(QKVb, Kb, VTb, CXb);

  gemm_bt<0, 0><<<dim3(DM / 128, MTOT / 128, 1), 256, 0, stream>>>(
      CXb, CXb, WoT, WoT, bo, bo, out, out, MTOT, DM, DM, DM, 1.f, 0);
}

// Round 6
// 223.332 us; speedup vs baseline: 1.5019x; 1.0543x over previous
//
#include <hip/hip_runtime.h>
#include <hip/hip_bf16.h>
#include <cstddef>

#define B_SZ 2
#define SEQ  2048
#define DM   1024
#define NH   16
#define HD   64
#define LAT  256
#define MTOT (B_SZ*SEQ)   // 4096
#define NQKV 1536
#define QSCALE 0.18033688011112042f  // 0.125 * log2(e)

typedef short bf16x8 __attribute__((ext_vector_type(8)));
typedef float floatx4 __attribute__((ext_vector_type(4)));
typedef unsigned short u16;

#if __has_builtin(__builtin_amdgcn_exp2f)
#define EXP2(x) __builtin_amdgcn_exp2f(x)
#else
#define EXP2(x) exp2f(x)
#endif

__device__ __forceinline__ u16 f2bf(float f) {
  union { float f; unsigned u; } a; a.f = f;
  unsigned r = a.u + 0x7FFFu + ((a.u >> 16) & 1u);  // RNE
  return (u16)(r >> 16);
}

__device__ __forceinline__ floatx4 mfma16(bf16x8 a, bf16x8 b, floatx4 c) {
  return __builtin_amdgcn_mfma_f32_16x16x32_bf16(a, b, c, 0, 0, 0);
}

// async global->LDS, 16B per lane; lds dest = wave-uniform base + lane*16
__device__ __forceinline__ void load16(const u16* g, u16* l) {
  __builtin_amdgcn_global_load_lds((const __attribute__((address_space(1))) unsigned*)g,
                                   (__attribute__((address_space(3))) unsigned*)l, 16, 0, 0);
}

// ---------------- mega prep: cast x | 6 weight transposes | bias concat ----------------
__device__ void transpose_tile(const float* __restrict__ W, u16* __restrict__ WT,
                               int K, int N, int k0, int n0, u16 (*t)[65]) {
  const int r = threadIdx.x >> 4;          // 0..15
  const int c4 = (threadIdx.x & 15) * 4;   // 0..60
#pragma unroll
  for (int s = 0; s < 4; s++) {
    int row = s * 16 + r;
    float4 v = *(const float4*)&W[(size_t)(k0 + row) * N + n0 + c4];
    t[row][c4 + 0] = f2bf(v.x); t[row][c4 + 1] = f2bf(v.y);
    t[row][c4 + 2] = f2bf(v.z); t[row][c4 + 3] = f2bf(v.w);
  }
  __syncthreads();
  const int r2 = threadIdx.x >> 2;          // 0..63 (out row = n)
  const int c8 = (threadIdx.x & 3) * 16;    // 0,16,32,48 (out col = k)
  __align__(16) u16 tmp[16];
#pragma unroll
  for (int i = 0; i < 16; i++) tmp[i] = t[c8 + i][r2];
  u16* dst = WT + (size_t)(n0 + r2) * K + k0 + c8;
  *(bf16x8*)dst       = *(const bf16x8*)&tmp[0];
  *(bf16x8*)(dst + 8) = *(const bf16x8*)&tmp[8];
}

__global__ __launch_bounds__(256)
void prep_k(const float* __restrict__ x, u16* __restrict__ xb,
            const float* __restrict__ Wq, const float* __restrict__ Wkd,
            const float* __restrict__ Wvd, const float* __restrict__ Wku,
            const float* __restrict__ Wvu, const float* __restrict__ Wo,
            u16* __restrict__ WstkT, u16* __restrict__ WkuT,
            u16* __restrict__ WvuT, u16* __restrict__ WoT,
            const float* __restrict__ bq, const float* __restrict__ bkd,
            const float* __restrict__ bvd, float* __restrict__ bqkv) {
  __shared__ u16 t[64][65];
  const int blk = blockIdx.x;
  if (blk < 4096) {                 // cast x -> bf16, 1 float4/thread
    int i = blk * 256 + threadIdx.x;
    float4 v = ((const float4*)x)[i];
    ushort4 o; o.x = f2bf(v.x); o.y = f2bf(v.y); o.z = f2bf(v.z); o.w = f2bf(v.w);
    ((ushort4*)xb)[i] = o;
  } else if (blk < 4352) {          // Wq^T -> WstkT[0:1024]
    int tt = blk - 4096;
    transpose_tile(Wq, WstkT, DM, DM, (tt >> 4) * 64, (tt & 15) * 64, t);
  } else if (blk < 4416) {          // Wkd^T -> WstkT[1024:1280]
    int tt = blk - 4352;
    transpose_tile(Wkd, WstkT + (size_t)DM * DM, DM, LAT, (tt >> 2) * 64, (tt & 3) * 64, t);
  } else if (blk < 4480) {          // Wvd^T -> WstkT[1280:1536]
    int tt = blk - 4416;
    transpose_tile(Wvd, WstkT + (size_t)1280 * DM, DM, LAT, (tt >> 2) * 64, (tt & 3) * 64, t);
  } else if (blk < 4544) {          // Wku^T
    int tt = blk - 4480;
    transpose_tile(Wku, WkuT, LAT, DM, (tt >> 4) * 64, (tt & 15) * 64, t);
  } else if (blk < 4608) {          // Wvu^T
    int tt = blk - 4544;
    transpose_tile(Wvu, WvuT, LAT, DM, (tt >> 4) * 64, (tt & 15) * 64, t);
  } else if (blk < 4864) {          // Wo^T
    int tt = blk - 4608;
    transpose_tile(Wo, WoT, DM, DM, (tt >> 4) * 64, (tt & 15) * 64, t);
  } else {                          // bias concat (6 blocks)
    int i = (blk - 4864) * 256 + threadIdx.x;
    float v = (i < 1024) ? bq[i] : (i < 1280) ? bkd[i - 1024] : bvd[i - 1280];
    bqkv[i] = v;
  }
}

// ---------------- GEMM: C = A * BT^T + bias ----------------
// TM x 64 block tile (TM=128 or 64) -> 2-4x more blocks/CU than 128x128 so the
// 2-barrier K-loop's vmcnt drain is hidden by co-resident blocks [R5 post-mortem].
// VT1: when blockIdx.z==1, write C in VT[bh][d][s] layout (fused V-transpose).
template<int TM, int OUT_BF16, int VT1>
__global__ __launch_bounds__(256)
void gemm_bt(const u16* __restrict__ A0, const u16* __restrict__ A1,
             const u16* __restrict__ BT0, const u16* __restrict__ BT1,
             const float* __restrict__ bias0, const float* __restrict__ bias1,
             void* __restrict__ C0, void* __restrict__ C1,
             int M, int N, int Kd, int lda, float qscale, int qcols) {
  constexpr int FM = TM / 32;       // frags per wave along M
  __shared__ u16 As[TM * 64];
  __shared__ u16 Bs[64 * 64];
  const u16* A  = blockIdx.z ? A1 : A0;
  const u16* BT = blockIdx.z ? BT1 : BT0;
  const float* bias = blockIdx.z ? bias1 : bias0;
  void* C = blockIdx.z ? C1 : C0;

  const int tid = threadIdx.x;
  const int m0 = blockIdx.y * TM, n0 = blockIdx.x * 64;
  const int wave = tid >> 6, lane = tid & 63;
  const int l15 = lane & 15, quad = lane >> 4;
  const int wm = (wave >> 1) * (TM / 2), wn = (wave & 1) * 32;

  floatx4 acc[FM][2];
#pragma unroll
  for (int i = 0; i < FM; i++)
#pragma unroll
    for (int j = 0; j < 2; j++) acc[i][j] = (floatx4){0.f, 0.f, 0.f, 0.f};

  const int tr = tid >> 3;          // 0..31
  const int tc8 = (tid & 7) * 8;
  const u16* Ag = A  + (size_t)(m0 + tr) * lda + tc8;
  const u16* Bg = BT + (size_t)(n0 + tr) * Kd + tc8;
  u16* AsW = &As[(size_t)tid * 8];
  u16* BsW = &Bs[(size_t)tid * 8];

  for (int k0 = 0; k0 < Kd; k0 += 64) {
    __syncthreads();
#pragma unroll
    for (int s = 0; s < FM; s++)
      load16(Ag + (size_t)(s * 32) * lda + k0, AsW + s * 2048);
#pragma unroll
    for (int s = 0; s < 2; s++)
      load16(Bg + (size_t)(s * 32) * Kd  + k0, BsW + s * 2048);
    __syncthreads();
#pragma unroll
    for (int kk = 0; kk < 2; kk++) {
      bf16x8 af[FM], bfr[2];
#pragma unroll
      for (int i = 0; i < FM; i++)
        af[i]  = *(const bf16x8*)&As[(wm + i * 16 + l15) * 64 + kk * 32 + quad * 8];
#pragma unroll
      for (int j = 0; j < 2; j++)
        bfr[j] = *(const bf16x8*)&Bs[(wn + j * 16 + l15) * 64 + kk * 32 + quad * 8];
#pragma unroll
      for (int i = 0; i < FM; i++)
#pragma unroll
        for (int j = 0; j < 2; j++)
          acc[i][j] = mfma16(af[i], bfr[j], acc[i][j]);
    }
  }

  if (VT1 && blockIdx.z == 1) {
    // write V in transposed per-head layout: VT[(b*16+h)*64+d][s]
#pragma unroll
    for (int i = 0; i < FM; i++) {
      int row = m0 + wm + i * 16 + quad * 4;    // b*2048 + s (s ≡ 0 mod 4)
      int bb = row >> 11, sb = row & 2047;
#pragma unroll
      for (int j = 0; j < 2; j++) {
        int col = n0 + wn + j * 16 + l15;       // h*64 + d
        float bv = bias[col];
        union { u16 u[4]; uint2 w2; } tv;
#pragma unroll
        for (int r = 0; r < 4; r++) tv.u[r] = f2bf(acc[i][j][r] + bv);
        *(uint2*)((u16*)C + ((size_t)(bb * 16 + (col >> 6)) * 64 + (col & 63)) * SEQ + sb) = tv.w2;
      }
    }
  } else {
#pragma unroll
    for (int i = 0; i < FM; i++) {
      int row = m0 + wm + i * 16 + quad * 4;
#pragma unroll
      for (int j = 0; j < 2; j++) {
        int col = n0 + wn + j * 16 + l15;
        float bv = bias[col];
        float sc = (col < qcols) ? qscale : 1.f;
#pragma unroll
        for (int r = 0; r < 4; r++) {
          float v = (acc[i][j][r] + bv) * sc;
          if (OUT_BF16) ((u16*)C)[(size_t)(row + r) * N + col] = f2bf(v);
          else          ((float*)C)[(size_t)(row + r) * N + col] = v;
        }
      }
    }
  }
}

// ---------------- fused attention ----------------
// grid (SEQ/64, B*NH), 4 waves share a 64-row q-tile; wave w handles keys [w*512,(w+1)*512).
// Fixed-shift softmax. Sᵀ=K·Qᵀ; P C-layout -> B-operand via wave-private LDS roundtrip.
// Occupancy is reg-bucket-bound at 2 waves/SIMD (88 VGPR + 64 AGPR > 128 bucket, m69) —
// so spend the ~100 free regs on ILP: register double-buffer of kf/vf (prefetch it+1),
// and batch all 4 qi phases so LDS roundtrip stalls once per iter and PV MFMAs are dense.
// DO NOT cap VGPRs tighter: (256,4) forced 64 VGPRs -> 580MB spill traffic [R4].
__global__ __launch_bounds__(256, 2)
void attn_fused(const u16* __restrict__ Q, const u16* __restrict__ K,
                const u16* __restrict__ VT, u16* __restrict__ CTX) {
  __shared__ float Ocmb[64][68];
  __shared__ float Lw[4][64];
  __shared__ u16 Plds[4][64][40];   // [wave][q(64)][key(32), stride 40]
  const int bh = blockIdx.y, b = bh >> 4, h = bh & 15;
  const int wave = threadIdx.x >> 6, lane = threadIdx.x & 63;
  const int l15 = lane & 15, quad = lane >> 4;
  const int q0 = blockIdx.x * 64;

  // Q as B-operand: qf[qi][h2] elem j = Q[q0+qi*16+l15][h*64 + h2*32 + quad*8 + j]
  bf16x8 qf[4][2];
  {
    const u16* Qp = Q + (size_t)(b * SEQ + q0 + l15) * NQKV + h * HD + quad * 8;
#pragma unroll
    for (int qi = 0; qi < 4; qi++)
#pragma unroll
      for (int h2 = 0; h2 < 2; h2++)
        qf[qi][h2] = *(const bf16x8*)(Qp + (size_t)qi * 16 * NQKV + h2 * 32);
  }
  const u16* Kp = K + (size_t)(b * SEQ) * DM + h * HD + quad * 8;
  const u16* Vp = VT + ((size_t)bh * HD + l15) * SEQ + quad * 8;

  floatx4 o[4][4];   // o[dt][qi]: ctxᵀ (rows = dim, cols = q)
#pragma unroll
  for (int dt = 0; dt < 4; dt++)
#pragma unroll
    for (int qi = 0; qi < 4; qi++) o[dt][qi] = (floatx4){0.f, 0.f, 0.f, 0.f};
  float ls[4] = {0.f, 0.f, 0.f, 0.f};

  const int kb0 = wave * 512;

  // register double-buffer for K/V fragments
  bf16x8 kfb[2][2][2], vfb[2][4];
#pragma unroll
  for (int ki = 0; ki < 2; ki++)
#pragma unroll
    for (int h2 = 0; h2 < 2; h2++)
      kfb[0][ki][h2] = *(const bf16x8*)(Kp + (size_t)(kb0 + ki * 16 + l15) * DM + h2 * 32);
#pragma unroll
  for (int dt = 0; dt < 4; dt++)
    vfb[0][dt] = *(const bf16x8*)(Vp + (size_t)(dt * 16) * SEQ + kb0);

#pragma unroll 2
  for (int it = 0; it < 16; ++it) {
    const int cur = it & 1, nxt = cur ^ 1;
    const int kb = kb0 + it * 32;
    // prefetch next iteration's K/V fragments (hidden under this iter's compute)
    if (it < 15) {
      const int kn = kb + 32;
#pragma unroll
      for (int ki = 0; ki < 2; ki++)
#pragma unroll
        for (int h2 = 0; h2 < 2; h2++)
          kfb[nxt][ki][h2] = *(const bf16x8*)(Kp + (size_t)(kn + ki * 16 + l15) * DM + h2 * 32);
#pragma unroll
      for (int dt = 0; dt < 4; dt++)
        vfb[nxt][dt] = *(const bf16x8*)(Vp + (size_t)(dt * 16) * SEQ + kn);
    }
    // ---- QK^T + exp + pack for all 4 qi ----
    unsigned pw[4][4];
#pragma unroll
    for (int qi = 0; qi < 4; qi++) {
#pragma unroll
      for (int ki = 0; ki < 2; ki++) {
        floatx4 z = (floatx4){0.f, 0.f, 0.f, 0.f};
        z = mfma16(kfb[cur][ki][0], qf[qi][0], z);
        z = mfma16(kfb[cur][ki][1], qf[qi][1], z);
        float p0 = EXP2(z[0]), p1 = EXP2(z[1]), p2 = EXP2(z[2]), p3 = EXP2(z[3]);
        ls[qi] += (p0 + p1) + (p2 + p3);
        unsigned u0 = __float_as_uint(p0) + 0x8000u;
        unsigned u1 = __float_as_uint(p1) + 0x8000u;
        unsigned u2 = __float_as_uint(p2) + 0x8000u;
        unsigned u3 = __float_as_uint(p3) + 0x8000u;
        pw[qi][ki * 2]     = __builtin_amdgcn_perm(u1, u0, 0x07060302u);
        pw[qi][ki * 2 + 1] = __builtin_amdgcn_perm(u3, u2, 0x07060302u);
      }
    }
    // ---- all LDS writes ----
#pragma unroll
    for (int qi = 0; qi < 4; qi++) {
      uint2 w0; w0.x = pw[qi][0]; w0.y = pw[qi][1];
      *(uint2*)&Plds[wave][qi * 16 + l15][quad * 4] = w0;
      uint2 w1; w1.x = pw[qi][2]; w1.y = pw[qi][3];
      *(uint2*)&Plds[wave][qi * 16 + l15][16 + quad * 4] = w1;
    }
    // ---- all reads + dense PV MFMA block ----
#pragma unroll
    for (int qi = 0; qi < 4; qi++) {
      bf16x8 pf = *(const bf16x8*)&Plds[wave][qi * 16 + l15][quad * 8];
#pragma unroll
      for (int dt = 0; dt < 4; dt++)
        o[dt][qi] = mfma16(vfb[cur][dt], pf, o[dt][qi]);
    }
  }

  // ---- per-wave l reduction ----
#pragma unroll
  for (int qi = 0; qi < 4; qi++) {
    float v = ls[qi];
    v += __shfl_xor(v, 16);
    v += __shfl_xor(v, 32);
    if (quad == 0) Lw[wave][qi * 16 + l15] = v;
  }
  // ---- serial combine through one buffer ----
  if (wave == 0) {
#pragma unroll
    for (int dt = 0; dt < 4; dt++)
#pragma unroll
      for (int qi = 0; qi < 4; qi++)
        *(floatx4*)&Ocmb[qi * 16 + l15][dt * 16 + quad * 4] = o[dt][qi];
  }
  __syncthreads();
  if (wave == 1) {
#pragma unroll
    for (int dt = 0; dt < 4; dt++)
#pragma unroll
      for (int qi = 0; qi < 4; qi++) {
        floatx4* pp = (floatx4*)&Ocmb[qi * 16 + l15][dt * 16 + quad * 4];
        *pp = *pp + o[dt][qi];
      }
  }
  __syncthreads();
  if (wave == 2) {
#pragma unroll
    for (int dt = 0; dt < 4; dt++)
#pragma unroll
      for (int qi = 0; qi < 4; qi++) {
        floatx4* pp = (floatx4*)&Ocmb[qi * 16 + l15][dt * 16 + quad * 4];
        *pp = *pp + o[dt][qi];
      }
  }
  __syncthreads();
  if (wave == 3) {
#pragma unroll
    for (int qi = 0; qi < 4; qi++) {
      int qq = qi * 16 + l15;
      float lt = Lw[0][qq] + Lw[1][qq] + Lw[2][qq] + Lw[3][qq];
      float inv = 1.f / lt;
      u16* Crow = CTX + (size_t)(b * SEQ + q0 + qq) * DM + h * HD + quad * 4;
#pragma unroll
      for (int dt = 0; dt < 4; dt++) {
        floatx4 ov = o[dt][qi] + *(const floatx4*)&Ocmb[qq][dt * 16 + quad * 4];
        union { u16 u[4]; uint2 w2; } tv;
#pragma unroll
        for (int r = 0; r < 4; r++) tv.u[r] = f2bf(ov[r] * inv);
        *(uint2*)(Crow + dt * 16) = tv.w2;
      }
    }
  }
}

// ---------------- launch ----------------
extern "C" void kernel_launch(void* const* d_in, const int* in_sizes, int n_in,
                              void* d_out, int out_size, void* d_ws, size_t ws_size,
                              hipStream_t stream) {
  const float* x   = (const float*)d_in[0];
  const float* Wq  = (const float*)d_in[1];
  const float* bq  = (const float*)d_in[2];
  const float* Wkd = (const float*)d_in[3];
  const float* bkd = (const float*)d_in[4];
  const float* Wvd = (const float*)d_in[5];
  const float* bvd = (const float*)d_in[6];
  const float* Wku = (const float*)d_in[7];
  const float* bku = (const float*)d_in[8];
  const float* Wvu = (const float*)d_in[9];
  const float* bvu = (const float*)d_in[10];
  const float* Wo  = (const float*)d_in[11];
  const float* bo  = (const float*)d_in[12];
  float* out = (float*)d_out;

  float* bqkv = (float*)d_ws;
  u16* p = (u16*)((char*)d_ws + 1536 * sizeof(float));
  u16* xb    = p; p += (size_t)MTOT * DM;
  u16* WstkT = p; p += (size_t)NQKV * DM;           // WqT | WkdT | WvdT
  u16* WkuT  = p; p += (size_t)DM * LAT;
  u16* WvuT  = p; p += (size_t)DM * LAT;
  u16* WoT   = p; p += (size_t)DM * DM;
  u16* QKVb  = p; p += (size_t)MTOT * NQKV;         // Q(pre-scaled) | KL | VL
  u16* Kb    = p; p += (size_t)MTOT * DM;
  u16* VTb   = p; p += (size_t)MTOT * DM;
  u16* CXb   = p; p += (size_t)MTOT * DM;

  prep_k<<<4870, 256, 0, stream>>>(x, xb, Wq, Wkd, Wvd, Wku, Wvu, Wo,
                                   WstkT, WkuT, WvuT, WoT, bq, bkd, bvd, bqkv);

  // QKV projection: 24x32 = 768 blocks (3/CU)
  gemm_bt<128, 1, 0><<<dim3(NQKV / 64, MTOT / 128, 1), 256, 0, stream>>>(
      xb, xb, WstkT, WstkT, bqkv, bqkv, QKVb, QKVb, MTOT, NQKV, DM, DM, QSCALE, DM);
  // K-up (row layout) + V-up (transposed layout): 16x32x2 = 1024 blocks (4/CU)
  gemm_bt<128, 1, 1><<<dim3(DM / 64, MTOT / 128, 2), 256, 0, stream>>>(
      QKVb + 1024, QKVb + 1280, WkuT, WvuT, bku, bvu, Kb, VTb, MTOT, DM, LAT, NQKV, 1.f, 0);

  attn_fused<<<dim3(SEQ / 64, B_SZ * NH), 256, 0, stream>>>(QKVb, Kb, VTb, CXb);

  // output projection: 16x64 = 1024 blocks (4/CU)
  gemm_bt<64, 0, 0><<<dim3(DM / 64, MTOT / 64, 1), 256, 0, stream>>>(
      CXb, CXb, WoT, WoT, bo, bo, out, out, MTOT, DM, DM, DM, 1.f, 0);
}